// Round 7
// baseline (224.286 us; speedup 1.0000x reference)
//
#include <hip/hip_runtime.h>

#define NFFT     4096
#define NC       2048      // complex FFT length (real-packed)
#define NHOP     1024
#define NK       2049
#define NBC      16
#define NSAMP    524288
#define NFRAMES  509
#define NT       256
#define STH      64        // k_smooth block size

#define A_COEFF 0.0022650046943f     // 1 - exp(-1/441)
#define R_COEFF 0.00022673165872f    // 1 - exp(-1/4410)
#define DB2LIN_LOG2 0.16609640474436812f  // log2(10)/20
#define DB_LOG2     6.02059991327962390f  // 20*log10(2)
#define PI_D 3.14159265358979323846264338327950288

// LDS swizzle: near-minimal aliasing at strides 256/32/4 and contiguous-8
#define SW(e) ((e) + 7*((e)>>5))
#define SWSZ 2489      // SW(2047)+1  -> 19912 B LDS = 8 blocks/CU
#define TWN  292       // radix-8 stage tables: 256(A) + 32(B) + 4(C)
// ws header (bytes): tw12@0, tw3t@8192, wbr@16384, pa@32768, pb@49152, mkq@65536
#define WSHDR 131072

__device__ __forceinline__ float2 cmul(float2 a, float2 b){
    return make_float2(a.x*b.x - a.y*b.y, a.x*b.y + a.y*b.x);
}
__device__ __forceinline__ float2 cmulc(float2 a, float2 b){   // a * conj(b)
    return make_float2(a.x*b.x + a.y*b.y, a.y*b.x - a.x*b.y);
}
__device__ __forceinline__ float2 f2add(float2 a, float2 b){ return make_float2(a.x+b.x, a.y+b.y); }
__device__ __forceinline__ float2 f2sub(float2 a, float2 b){ return make_float2(a.x-b.x, a.y-b.y); }

#define RSQRT2 0.70710678118654752f

// mixed-radix (8,8,8,4) digit scramble: slot p = 256rA+32rB+4rC+rD holds bin
// k = rA + 8rB + 64rC + 512rD
__device__ __forceinline__ int revm(int p){
    return (p>>8) + 8*((p>>5)&7) + 64*((p>>2)&7) + 512*(p&3);
}
__device__ __forceinline__ int pmap(int k){
    return ((k&7)<<8) | (((k>>3)&7)<<5) | (((k>>6)&7)<<2) | ((k>>9)&3);
}
// pair-index m (0..1023) -> slot p with (p&3) in {0,1}  <=>  bin k < 1024
__device__ __forceinline__ int p_of_m(int m){ return ((m>>1)<<2) | (m&1); }

// ---------------- radix-8 DIF round (forward): butterfly then twiddle ----------------
template<int S>
__device__ __forceinline__ void r8_fwd(float2* s, const float4* __restrict__ tw12,
                                       const float2* __restrict__ tw3t,
                                       int base, int n, int toff){
    float2 d[8];
#pragma unroll
    for (int q = 0; q < 8; ++q) d[q] = s[SW(base + S*q)];
    float2 EA0=f2add(d[0],d[4]), EA1=f2sub(d[0],d[4]);
    float2 EB0=f2add(d[2],d[6]), EB1=f2sub(d[2],d[6]);
    float2 OA0=f2add(d[1],d[5]), OA1=f2sub(d[1],d[5]);
    float2 OB0=f2add(d[3],d[7]), OB1=f2sub(d[3],d[7]);
    float2 E0=f2add(EA0,EB0), E2=f2sub(EA0,EB0);
    float2 E1=make_float2(EA1.x+EB1.y, EA1.y-EB1.x);   // EA1 - i*EB1
    float2 E3=make_float2(EA1.x-EB1.y, EA1.y+EB1.x);   // EA1 + i*EB1
    float2 O0=f2add(OA0,OB0), O2=f2sub(OA0,OB0);
    float2 O1=make_float2(OA1.x+OB1.y, OA1.y-OB1.x);
    float2 O3=make_float2(OA1.x-OB1.y, OA1.y+OB1.x);
    const float c = RSQRT2;
    float2 t1=make_float2(c*(O1.x+O1.y), c*(O1.y-O1.x));   // w8^1 * O1
    float2 u2=make_float2(O2.y, -O2.x);                    // -i * O2
    float2 v3=make_float2(c*(O3.y-O3.x), -c*(O3.x+O3.y));  // w8^3 * O3
    float4 w12 = tw12[toff + n];
    float2 w1 = make_float2(w12.x, w12.y), w2 = make_float2(w12.z, w12.w);
    float2 w3 = tw3t[toff + n];
    float2 w4 = cmul(w2,w2), w5 = cmul(w2,w3), w6 = cmul(w3,w3), w7 = cmul(w3,w4);
    s[SW(base)]     = f2add(E0,O0);
    s[SW(base+S)]   = cmul(f2add(E1,t1), w1);
    s[SW(base+2*S)] = cmul(f2add(E2,u2), w2);
    s[SW(base+3*S)] = cmul(f2add(E3,v3), w3);
    s[SW(base+4*S)] = cmul(f2sub(E0,O0), w4);
    s[SW(base+5*S)] = cmul(f2sub(E1,t1), w5);
    s[SW(base+6*S)] = cmul(f2sub(E2,u2), w6);
    s[SW(base+7*S)] = cmul(f2sub(E3,v3), w7);
}

// ---------------- radix-8 DIT round (inverse): conj-twiddle then inverse butterfly ----
template<int S>
__device__ __forceinline__ void r8_inv(float2* s, const float4* __restrict__ tw12,
                                       const float2* __restrict__ tw3t,
                                       int base, int n, int toff){
    float2 d[8];
#pragma unroll
    for (int q = 0; q < 8; ++q) d[q] = s[SW(base + S*q)];
    float4 w12 = tw12[toff + n];
    float2 w1 = make_float2(w12.x, w12.y), w2 = make_float2(w12.z, w12.w);
    float2 w3 = tw3t[toff + n];
    float2 w4 = cmul(w2,w2), w5 = cmul(w2,w3), w6 = cmul(w3,w3), w7 = cmul(w3,w4);
    d[1]=cmulc(d[1],w1); d[2]=cmulc(d[2],w2); d[3]=cmulc(d[3],w3); d[4]=cmulc(d[4],w4);
    d[5]=cmulc(d[5],w5); d[6]=cmulc(d[6],w6); d[7]=cmulc(d[7],w7);
    float2 EA0=f2add(d[0],d[4]), EA1=f2sub(d[0],d[4]);
    float2 EB0=f2add(d[2],d[6]), EB1=f2sub(d[2],d[6]);
    float2 OA0=f2add(d[1],d[5]), OA1=f2sub(d[1],d[5]);
    float2 OB0=f2add(d[3],d[7]), OB1=f2sub(d[3],d[7]);
    float2 E0=f2add(EA0,EB0), E2=f2sub(EA0,EB0);
    float2 E1=make_float2(EA1.x-EB1.y, EA1.y+EB1.x);   // EA1 + i*EB1
    float2 E3=make_float2(EA1.x+EB1.y, EA1.y-EB1.x);
    float2 O0=f2add(OA0,OB0), O2=f2sub(OA0,OB0);
    float2 O1=make_float2(OA1.x-OB1.y, OA1.y+OB1.x);
    float2 O3=make_float2(OA1.x+OB1.y, OA1.y-OB1.x);
    const float c = RSQRT2;
    float2 t1=make_float2(c*(O1.x-O1.y), c*(O1.y+O1.x));    // conj(w8)*O1
    float2 u2=make_float2(-O2.y, O2.x);                     // +i*O2
    float2 v3=make_float2(-c*(O3.x+O3.y), c*(O3.x-O3.y));   // conj(w8^3)*O3
    s[SW(base)]     = f2add(E0,O0);
    s[SW(base+S)]   = f2add(E1,t1);
    s[SW(base+2*S)] = f2add(E2,u2);
    s[SW(base+3*S)] = f2add(E3,v3);
    s[SW(base+4*S)] = f2sub(E0,O0);
    s[SW(base+5*S)] = f2sub(E1,t1);
    s[SW(base+6*S)] = f2sub(E2,u2);
    s[SW(base+7*S)] = f2sub(E3,v3);
}

// forward: natural input -> scrambled slots (mixed-radix reversal)
__device__ __forceinline__ void fft_fwd(float2* s, const float4* __restrict__ tw12,
                                        const float2* __restrict__ tw3t, int tid){
    r8_fwd<256>(s, tw12, tw3t, tid, tid, 0);
    __syncthreads();
    r8_fwd<32>(s, tw12, tw3t, (tid>>5)*256 + (tid&31), tid&31, 256);
    __syncthreads();
    r8_fwd<4>(s, tw12, tw3t, (tid>>2)*32 + (tid&3), tid&3, 288);
    __syncthreads();
    {   // radix-4 span-1, trivial twiddle; 2 groups/thread (contiguous 8)
        int g8 = 8*tid;
#pragma unroll
        for (int h = 0; h < 2; ++h) {
            int b4 = g8 + 4*h;
            float2 x0=s[SW(b4)], x1=s[SW(b4+1)], x2=s[SW(b4+2)], x3=s[SW(b4+3)];
            float2 A0=f2add(x0,x2), A1=f2sub(x0,x2);
            float2 B0=f2add(x1,x3), B1=f2sub(x1,x3);
            s[SW(b4)]   = f2add(A0,B0);
            s[SW(b4+1)] = make_float2(A1.x + B1.y, A1.y - B1.x);  // A1 - i*B1
            s[SW(b4+2)] = f2sub(A0,B0);
            s[SW(b4+3)] = make_float2(A1.x - B1.y, A1.y + B1.x);  // A1 + i*B1
        }
    }
    __syncthreads();
}

// inverse: scrambled slots -> natural time order (unnormalized)
__device__ __forceinline__ void fft_inv(float2* s, const float4* __restrict__ tw12,
                                        const float2* __restrict__ tw3t, int tid){
    {   // radix-4 span-1 inverse
        int g8 = 8*tid;
#pragma unroll
        for (int h = 0; h < 2; ++h) {
            int b4 = g8 + 4*h;
            float2 z0=s[SW(b4)], z1=s[SW(b4+1)], z2=s[SW(b4+2)], z3=s[SW(b4+3)];
            float2 A0=f2add(z0,z2), A1=f2sub(z0,z2);
            float2 B0=f2add(z1,z3), B1=f2sub(z1,z3);
            s[SW(b4)]   = f2add(A0,B0);
            s[SW(b4+1)] = make_float2(A1.x - B1.y, A1.y + B1.x);  // A1 + i*B1
            s[SW(b4+2)] = f2sub(A0,B0);
            s[SW(b4+3)] = make_float2(A1.x + B1.y, A1.y - B1.x);  // A1 - i*B1
        }
    }
    __syncthreads();
    r8_inv<4>(s, tw12, tw3t, (tid>>2)*32 + (tid&3), tid&3, 288);
    __syncthreads();
    r8_inv<32>(s, tw12, tw3t, (tid>>5)*256 + (tid&31), tid&31, 256);
    __syncthreads();
    r8_inv<256>(s, tw12, tw3t, tid, tid, 0);
    __syncthreads();
}

// q = {th, ks, 1/kw, slope}; ke = 2*th - ks
__device__ __forceinline__ float gr_of(float a, float4 q){
    float mag_db = DB_LOG2 * log2f(fmaxf(a, 1e-8f));
    float over = mag_db - q.x;
    float hard = (mag_db < q.x) ? 0.0f : over*q.w;
    float kf = fminf(fmaxf((mag_db - q.y)*q.z, 0.0f), 1.0f);
    float kneeg = kf*kf*over*q.w;
    float ke = 2.0f*q.x - q.y;
    return (mag_db >= q.y && mag_db <= ke) ? kneeg : hard;
}

__device__ __forceinline__ float2 scale_bin(float2 X, float g){
    float a = sqrtf(X.x*X.x + X.y*X.y);
    if (a >= 1e-8f) return make_float2(g*X.x, g*X.y);
    if (a > 0.f)  { float sc = g*1e-8f/a; return make_float2(sc*X.x, sc*X.y); }
    return make_float2(g*1e-8f, 0.f);
}

// bin index for thread-order gain slot q
__device__ __forceinline__ int bin_of_q(int q){
    if (q >= 2048) return 1024;
    int jj = q >> 8, t = q & 255;
    int m = t + 256*(jj>>1);
    int k = revm(p_of_m(m));
    if (jj & 1) return (k == 0) ? 2048 : 2048 - k;
    return k;
}

// ---------------- init: twiddles + pair tables + makeup table ----------------
__global__ __launch_bounds__(NT) void k_init(
    const float* __restrict__ thr, const float* __restrict__ ratio,
    const float* __restrict__ knee, const float* __restrict__ makeup,
    float4* __restrict__ tw12, float2* __restrict__ tw3t,
    float2* __restrict__ wbr, float4* __restrict__ pa, float4* __restrict__ pb,
    float* __restrict__ mkq)
{
    int i = blockIdx.x*NT + threadIdx.x;
    if (i < TWN) {
        int n, len;
        if (i < 256)      { n = i;       len = 2048; }
        else if (i < 288) { n = i - 256; len = 256;  }
        else              { n = i - 288; len = 32;   }
        double ang = -2.0*PI_D*(double)n/(double)len;
        tw12[i] = make_float4((float)cos(ang), (float)sin(ang),
                              (float)cos(2.0*ang), (float)sin(2.0*ang));
        tw3t[i] = make_float2((float)cos(3.0*ang), (float)sin(3.0*ang));
    } else if (i < TWN + 1024) {
        int m = i - TWN;
        int k = revm(p_of_m(m));
        int k2 = (k == 0) ? 2048 : 2048 - k;
        double ang = -PI_D*(double)k/2048.0;   // E(k/4096)
        wbr[m] = make_float2((float)cos(ang), (float)sin(ang));
        float th = thr[k], ra = ratio[k], kw = knee[k];
        pa[m] = make_float4(th, th - 0.5f*kw, 1.0f/kw, 1.0f - 1.0f/ra);
        th = thr[k2]; ra = ratio[k2]; kw = knee[k2];
        pb[m] = make_float4(th, th - 0.5f*kw, 1.0f/kw, 1.0f - 1.0f/ra);
    } else if (i < TWN + 1024 + NK) {
        int q = i - TWN - 1024;
        mkq[q] = exp2f(makeup[bin_of_q(q)] * DB2LIN_LOG2);   // 10^(mk/20)
    }
}

// ---------------- kernel 1: real-packed STFT; spec + gr (thread-order) ----------------
template<int STORESPEC>
__global__ __launch_bounds__(NT, 8) void k_fwd(
    const float* __restrict__ audio, const float* __restrict__ window,
    const float* __restrict__ thr, const float* __restrict__ ratio,
    const float* __restrict__ knee,
    const float4* __restrict__ tw12, const float2* __restrict__ tw3t,
    const float2* __restrict__ wbr, const float4* __restrict__ pa,
    const float4* __restrict__ pb,
    float* __restrict__ gr, float2* __restrict__ spec)
{
    __shared__ float2 s[SWSZ];
    const int tid = threadIdx.x;
    const int blk = blockIdx.x;
    const int bc  = blk / NFRAMES;
    const int f   = blk - bc*NFRAMES;

    const float4* src4 = (const float4*)(audio + (size_t)bc*NSAMP + (size_t)f*NHOP);
    const float4* win4 = (const float4*)window;
    for (int m = tid; m < NC/2; m += NT) {
        float4 u = src4[m], w = win4[m];
        s[SW(2*m)]   = make_float2(u.x*w.x, u.y*w.y);   // z[n] = x[2n]w + i x[2n+1]w
        s[SW(2*m+1)] = make_float2(u.z*w.z, u.w*w.w);
    }
    __syncthreads();
    fft_fwd(s, tw12, tw3t, tid);

    const size_t row = ((size_t)bc*NFRAMES + f) * NK;
    if (STORESPEC) {
        float4* sp4 = (float4*)(spec + ((size_t)bc*NFRAMES + f) * NC);
        for (int m = tid; m < NC/2; m += NT) {
            float2 a = s[SW(2*m)], b = s[SW(2*m+1)];
            sp4[m] = make_float4(a.x, a.y, b.x, b.y);
        }
    }
#pragma unroll
    for (int j = 0; j < 4; ++j) {
        int m  = tid + NT*j;
        int p  = p_of_m(m);
        int k  = revm(p);
        int p2 = pmap((2048 - k) & 2047);
        float2 Zk  = s[SW(p)];
        float2 Zk2 = s[SW(p2)];
        float2 Ze = make_float2(0.5f*(Zk.x + Zk2.x), 0.5f*(Zk.y - Zk2.y));
        float2 Zo = make_float2(0.5f*(Zk.y + Zk2.y), -0.5f*(Zk.x - Zk2.x));
        float2 W  = wbr[m];
        float2 V  = cmul(W, Zo);
        float2 Xk  = f2add(Ze, V);                              // X[k]
        float2 Xk2 = make_float2(Ze.x - V.x, V.y - Ze.y);       // X[2048-k]
        gr[row + tid + NT*(2*j)]     = gr_of(sqrtf(Xk.x*Xk.x + Xk.y*Xk.y),   pa[m]);
        gr[row + tid + NT*(2*j + 1)] = gr_of(sqrtf(Xk2.x*Xk2.x + Xk2.y*Xk2.y), pb[m]);
    }
    if (tid == 0) {   // self-paired bin 1024 at slot pmap(1024)=2 -> q=2048
        float2 Z = s[SW(2)];
        float th = thr[1024], ra = ratio[1024], kw = knee[1024];
        float4 q = make_float4(th, th - 0.5f*kw, 1.0f/kw, 1.0f - 1.0f/ra);
        gr[row + 2048] = gr_of(sqrtf(Z.x*Z.x + Z.y*Z.y), q);
    }
}

// ---------------- kernel 2: attack/release scan; gr(dB) -> linear gain ----------------
__global__ __launch_bounds__(STH) void k_smooth(
    float* __restrict__ gr, const float* __restrict__ mkq)
{
    int gid = blockIdx.x*STH + threadIdx.x;
    if (gid >= NBC*NK) return;
    int bc = gid / NK;
    int q  = gid - bc*NK;
    float mkLin = mkq[q];
    float* p = gr + (size_t)bc*NFRAMES*NK + q;

    float env = 0.f;
    float cur[8], nxt[8];
#pragma unroll
    for (int d = 0; d < 8; ++d) cur[d] = p[(size_t)d*NK];
    for (int c = 0; c < NFRAMES; c += 8) {
#pragma unroll
        for (int d = 0; d < 8; ++d) {              // prefetch next batch early
            int fn = c + 8 + d;
            if (fn < NFRAMES) nxt[d] = p[(size_t)fn*NK];
        }
#pragma unroll
        for (int d = 0; d < 8; ++d)
            if (c + d < NFRAMES) cur[d] = exp2f(cur[d] * -DB2LIN_LOG2);  // tgt
#pragma unroll
        for (int d = 0; d < 8; ++d)
            if (c + d < NFRAMES) {
                float tgt = cur[d];
                float coeff = (tgt < env) ? A_COEFF : R_COEFF;
                env = fmaf(coeff, tgt - env, env);
                cur[d] = fmaxf(env, 1e-8f) * mkLin;   // linear gain (log/exp cancels)
            }
#pragma unroll
        for (int d = 0; d < 8; ++d)
            if (c + d < NFRAMES) p[(size_t)(c+d)*NK] = cur[d];
#pragma unroll
        for (int d = 0; d < 8; ++d) cur[d] = nxt[d];
    }
}

// scale + repack bins in LDS (shared by both k_inv modes)
__device__ __forceinline__ void scale_repack(float2* s, const float* __restrict__ g,
                                             const float2* __restrict__ wbr, int tid){
#pragma unroll
    for (int j = 0; j < 4; ++j) {
        int m  = tid + NT*j;
        int p  = p_of_m(m);
        int k  = revm(p);
        int p2 = pmap((2048 - k) & 2047);
        float2 Zk  = s[SW(p)];
        float2 Zk2 = s[SW(p2)];
        float2 Ze = make_float2(0.5f*(Zk.x + Zk2.x), 0.5f*(Zk.y - Zk2.y));
        float2 Zo = make_float2(0.5f*(Zk.y + Zk2.y), -0.5f*(Zk.x - Zk2.x));
        float2 W  = wbr[m];
        float2 V  = cmul(W, Zo);
        float2 Xk  = f2add(Ze, V);
        float2 Xk2 = make_float2(Ze.x - V.x, V.y - Ze.y);
        float2 XSk  = scale_bin(Xk,  g[tid + NT*(2*j)]);
        float2 XSk2 = scale_bin(Xk2, g[tid + NT*(2*j + 1)]);
        // repack: Z'[k] = E + i*conj(W)*P ; Z'[k2] = conj(E) + i*W*conj(P)
        float2 E = make_float2(0.5f*(XSk.x + XSk2.x), 0.5f*(XSk.y - XSk2.y));
        float2 P = make_float2(0.5f*(XSk.x - XSk2.x), 0.5f*(XSk.y + XSk2.y));
        float2 Wc = make_float2(W.x, -W.y);
        float2 Q  = cmul(Wc, P);
        float2 Pc = make_float2(P.x, -P.y);
        float2 R  = cmul(W, Pc);
        s[SW(p)]  = make_float2(E.x - Q.y, E.y + Q.x);
        s[SW(p2)] = make_float2(E.x - R.y, R.x - E.y);
    }
    if (tid == 0) {   // self-paired bin 1024 at slot 2
        float2 Z  = s[SW(2)];
        float2 X  = make_float2(Z.x, -Z.y);
        float2 XS = scale_bin(X, g[2048]);
        s[SW(2)] = make_float2(XS.x, -XS.y);
    }
}

// MODE 0: read spec, scale, ifft, overwrite spec row with windowed ca
// MODE 1: fallback — recompute fwd FFT from audio, scale, ifft, RMW out (4 passes)
template<int MODE>
__global__ __launch_bounds__(NT, 8) void k_inv(
    const float* __restrict__ audio, const float* __restrict__ window,
    const float* __restrict__ gains,
    const float4* __restrict__ tw12, const float2* __restrict__ tw3t,
    const float2* __restrict__ wbr,
    float2* __restrict__ spec, float* __restrict__ out, int pass, int nfp)
{
    __shared__ float2 s[SWSZ];
    const int tid = threadIdx.x;
    const int blk = blockIdx.x;
    int bc, f;
    if (MODE == 0) { bc = blk / NFRAMES; f = blk - bc*NFRAMES; }
    else           { bc = blk / nfp;     f = pass + 4*(blk - bc*nfp); }

    const float4* win4 = (const float4*)window;
    float2* sp = spec + ((size_t)bc*NFRAMES + f) * NC;
    if (MODE == 0) {
        const float4* sp4 = (const float4*)sp;
        for (int m = tid; m < NC/2; m += NT) {
            float4 v = sp4[m];
            s[SW(2*m)]   = make_float2(v.x, v.y);
            s[SW(2*m+1)] = make_float2(v.z, v.w);
        }
        __syncthreads();
    } else {
        const float4* src4 = (const float4*)(audio + (size_t)bc*NSAMP + (size_t)f*NHOP);
        for (int m = tid; m < NC/2; m += NT) {
            float4 u = src4[m], w = win4[m];
            s[SW(2*m)]   = make_float2(u.x*w.x, u.y*w.y);
            s[SW(2*m+1)] = make_float2(u.z*w.z, u.w*w.w);
        }
        __syncthreads();
        fft_fwd(s, tw12, tw3t, tid);
    }

    scale_repack(s, gains + ((size_t)bc*NFRAMES + f) * NK, wbr, tid);
    __syncthreads();
    fft_inv(s, tw12, tw3t, tid);

    const float invn = 1.0f/2048.0f;
    if (MODE == 0) {
        float4* dst4 = (float4*)sp;      // overwrite spec row with windowed ifft (ca)
        for (int m = tid; m < NC/2; m += NT) {
            float2 z0 = s[SW(2*m)], z1 = s[SW(2*m+1)];
            float4 w = win4[m];
            dst4[m] = make_float4(z0.x*w.x*invn, z0.y*w.y*invn,
                                  z1.x*w.z*invn, z1.y*w.w*invn);
        }
    } else {
        float2* dst2 = (float2*)(out + (size_t)bc*NSAMP + (size_t)f*NHOP);
        const float2* win2 = (const float2*)window;
        for (int n = tid; n < NC; n += NT) {
            float2 z = s[SW(n)];
            float2 w = win2[n];
            float2 o = dst2[n];
            o.x += z.x * w.x * invn;
            o.y += z.y * w.y * invn;
            dst2[n] = o;
        }
    }
}

// ---------------- kernel 4: overlap-add gather (each ca byte read exactly once) ----------------
__global__ __launch_bounds__(NT) void k_ola(
    const float* __restrict__ ca, float* __restrict__ out)
{
    const int blk = blockIdx.x;
    const int bc = blk >> 9;          // 512 tiles of 1024 samples
    const int ti = blk & 511;
    const int tid = threadIdx.x;
    float4 acc = make_float4(0.f, 0.f, 0.f, 0.f);
    int flo = ti - 3; if (flo < 0) flo = 0;
    int fhi = ti; if (fhi > NFRAMES - 1) fhi = NFRAMES - 1;
    for (int f = flo; f <= fhi; ++f) {
        const float4* row = (const float4*)(ca + ((size_t)bc*NFRAMES + f) * NFFT);
        float4 v = row[(ti - f)*256 + tid];
        acc.x += v.x; acc.y += v.y; acc.z += v.z; acc.w += v.w;
    }
    ((float4*)(out + (size_t)bc*NSAMP))[ti*256 + tid] = acc;
}

extern "C" void kernel_launch(void* const* d_in, const int* in_sizes, int n_in,
                              void* d_out, int out_size, void* d_ws, size_t ws_size,
                              hipStream_t stream)
{
    const float* audio  = (const float*)d_in[0];
    const float* window = (const float*)d_in[1];
    const float* thr    = (const float*)d_in[2];
    const float* ratio  = (const float*)d_in[3];
    const float* makeup = (const float*)d_in[4];
    const float* knee   = (const float*)d_in[5];
    float* out = (float*)d_out;

    float4* tw12 = (float4*)d_ws;
    float2* tw3t = (float2*)((char*)d_ws + 8192);
    float2* wbr  = (float2*)((char*)d_ws + 16384);
    float4* pa   = (float4*)((char*)d_ws + 32768);
    float4* pb   = (float4*)((char*)d_ws + 49152);
    float*  mkq  = (float*)((char*)d_ws + 65536);
    float*  gr   = (float*)((char*)d_ws + WSHDR);
    size_t grBytes = (size_t)NBC*NFRAMES*NK*sizeof(float);
    float2* spec = (float2*)((char*)d_ws + WSHDR + grBytes);
    size_t need = WSHDR + grBytes + (size_t)NBC*NFRAMES*NC*sizeof(float2);
    int hasSpec = (ws_size >= need) ? 1 : 0;

    dim3 blkd(NT);
    k_init<<<dim3((TWN + 1024 + NK + NT - 1)/NT), blkd, 0, stream>>>(
        thr, ratio, knee, makeup, tw12, tw3t, wbr, pa, pb, mkq);

    if (hasSpec) {
        k_fwd<1><<<dim3(NBC*NFRAMES), blkd, 0, stream>>>(
            audio, window, thr, ratio, knee, tw12, tw3t, wbr, pa, pb, gr, spec);
        k_smooth<<<dim3((NBC*NK + STH - 1)/STH), dim3(STH), 0, stream>>>(gr, mkq);
        k_inv<0><<<dim3(NBC*NFRAMES), blkd, 0, stream>>>(
            audio, window, gr, tw12, tw3t, wbr, spec, out, 0, 0);
        k_ola<<<dim3(NBC*512), blkd, 0, stream>>>((const float*)spec, out);
    } else {
        hipMemsetAsync(d_out, 0, (size_t)out_size*sizeof(float), stream);
        k_fwd<0><<<dim3(NBC*NFRAMES), blkd, 0, stream>>>(
            audio, window, thr, ratio, knee, tw12, tw3t, wbr, pa, pb, gr, spec);
        k_smooth<<<dim3((NBC*NK + STH - 1)/STH), dim3(STH), 0, stream>>>(gr, mkq);
        for (int pass = 0; pass < 4; ++pass) {
            int nfp = (NFRAMES - pass + 3) / 4;
            k_inv<1><<<dim3(NBC*nfp), blkd, 0, stream>>>(
                audio, window, gr, tw12, tw3t, wbr, spec, out, pass, nfp);
        }
    }
}

// Round 8
// 212.994 us; speedup vs baseline: 1.0530x; 1.0530x over previous
//
#include <hip/hip_runtime.h>

#define NFFT     4096
#define NC       2048      // complex FFT length (real-packed)
#define NHOP     1024
#define NK       2049
#define NBC      16
#define NSAMP    524288
#define NFRAMES  509
#define NT       256
#define STH      64        // k_smooth block size
#define CAST4    1025      // spec row stride in float4 (1024 pairs + bin1024)

#define A_COEFF 0.0022650046943f     // 1 - exp(-1/441)
#define R_COEFF 0.00022673165872f    // 1 - exp(-1/4410)
#define DB2LIN_LOG2 0.16609640474436812f  // log2(10)/20
#define DB_LOG2     6.02059991327962390f  // 20*log10(2)
#define PI_D 3.14159265358979323846264338327950288

// LDS swizzle: ~2-way max at every FFT stage
#define SW(e) ((e) + 7*((e)>>5))
#define SWSZ 2489      // SW(2047)+1  -> 19912 B LDS = 8 blocks/CU
#define TWN  292       // radix-8 stage tables: 256(A) + 32(B) + 4(C)
// ws header (bytes): tw12@0, tw3t@8192, wp@16384, pa@32768, pb@49152, mkq@65536
#define WSHDR 131072

__device__ __forceinline__ float2 cmul(float2 a, float2 b){
    return make_float2(a.x*b.x - a.y*b.y, a.x*b.y + a.y*b.x);
}
__device__ __forceinline__ float2 cmulc(float2 a, float2 b){   // a * conj(b)
    return make_float2(a.x*b.x + a.y*b.y, a.y*b.x - a.x*b.y);
}
__device__ __forceinline__ float2 f2add(float2 a, float2 b){ return make_float2(a.x+b.x, a.y+b.y); }
__device__ __forceinline__ float2 f2sub(float2 a, float2 b){ return make_float2(a.x-b.x, a.y-b.y); }

#define RSQRT2 0.70710678118654752f

// mixed-radix (8,8,8,4) digit scramble: slot p = 256rA+32rB+4rC+rD holds bin
// k = rA + 8rB + 64rC + 512rD   (host-side tables only)
__device__ __forceinline__ int revm(int p){
    return (p>>8) + 8*((p>>5)&7) + 64*((p>>2)&7) + 512*(p&3);
}
__device__ __forceinline__ int pmap(int k){
    return ((k&7)<<8) | (((k>>3)&7)<<5) | (((k>>6)&7)<<2) | ((k>>9)&3);
}
__device__ __forceinline__ int p_of_m(int m){ return ((m>>1)<<2) | (m&1); }

// ---------------- radix-8 forward core: butterfly then twiddle, in place ----------------
__device__ __forceinline__ void r8f(float2* d, const float4* __restrict__ tw12,
                                    const float2* __restrict__ tw3t, int n, int toff){
    float2 EA0=f2add(d[0],d[4]), EA1=f2sub(d[0],d[4]);
    float2 EB0=f2add(d[2],d[6]), EB1=f2sub(d[2],d[6]);
    float2 OA0=f2add(d[1],d[5]), OA1=f2sub(d[1],d[5]);
    float2 OB0=f2add(d[3],d[7]), OB1=f2sub(d[3],d[7]);
    float2 E0=f2add(EA0,EB0), E2=f2sub(EA0,EB0);
    float2 E1=make_float2(EA1.x+EB1.y, EA1.y-EB1.x);   // EA1 - i*EB1
    float2 E3=make_float2(EA1.x-EB1.y, EA1.y+EB1.x);   // EA1 + i*EB1
    float2 O0=f2add(OA0,OB0), O2=f2sub(OA0,OB0);
    float2 O1=make_float2(OA1.x+OB1.y, OA1.y-OB1.x);
    float2 O3=make_float2(OA1.x-OB1.y, OA1.y+OB1.x);
    const float c = RSQRT2;
    float2 t1=make_float2(c*(O1.x+O1.y), c*(O1.y-O1.x));   // w8^1 * O1
    float2 u2=make_float2(O2.y, -O2.x);                    // -i * O2
    float2 v3=make_float2(c*(O3.y-O3.x), -c*(O3.x+O3.y));  // w8^3 * O3
    float4 w12 = tw12[toff + n];
    float2 w1 = make_float2(w12.x, w12.y), w2 = make_float2(w12.z, w12.w);
    float2 w3 = tw3t[toff + n];
    float2 w4 = cmul(w2,w2), w5 = cmul(w2,w3), w6 = cmul(w3,w3), w7 = cmul(w3,w4);
    d[0] = f2add(E0,O0);
    d[1] = cmul(f2add(E1,t1), w1);
    d[2] = cmul(f2add(E2,u2), w2);
    d[3] = cmul(f2add(E3,v3), w3);
    d[4] = cmul(f2sub(E0,O0), w4);
    d[5] = cmul(f2sub(E1,t1), w5);
    d[6] = cmul(f2sub(E2,u2), w6);
    d[7] = cmul(f2sub(E3,v3), w7);
}

// ---------------- radix-8 inverse core: conj-twiddle then inverse butterfly ----------------
__device__ __forceinline__ void r8i(float2* d, const float4* __restrict__ tw12,
                                    const float2* __restrict__ tw3t, int n, int toff){
    float4 w12 = tw12[toff + n];
    float2 w1 = make_float2(w12.x, w12.y), w2 = make_float2(w12.z, w12.w);
    float2 w3 = tw3t[toff + n];
    float2 w4 = cmul(w2,w2), w5 = cmul(w2,w3), w6 = cmul(w3,w3), w7 = cmul(w3,w4);
    d[1]=cmulc(d[1],w1); d[2]=cmulc(d[2],w2); d[3]=cmulc(d[3],w3); d[4]=cmulc(d[4],w4);
    d[5]=cmulc(d[5],w5); d[6]=cmulc(d[6],w6); d[7]=cmulc(d[7],w7);
    float2 EA0=f2add(d[0],d[4]), EA1=f2sub(d[0],d[4]);
    float2 EB0=f2add(d[2],d[6]), EB1=f2sub(d[2],d[6]);
    float2 OA0=f2add(d[1],d[5]), OA1=f2sub(d[1],d[5]);
    float2 OB0=f2add(d[3],d[7]), OB1=f2sub(d[3],d[7]);
    float2 E0=f2add(EA0,EB0), E2=f2sub(EA0,EB0);
    float2 E1=make_float2(EA1.x-EB1.y, EA1.y+EB1.x);   // EA1 + i*EB1
    float2 E3=make_float2(EA1.x+EB1.y, EA1.y-EB1.x);
    float2 O0=f2add(OA0,OB0), O2=f2sub(OA0,OB0);
    float2 O1=make_float2(OA1.x-OB1.y, OA1.y+OB1.x);
    float2 O3=make_float2(OA1.x+OB1.y, OA1.y-OB1.x);
    const float c = RSQRT2;
    float2 t1=make_float2(c*(O1.x-O1.y), c*(O1.y+O1.x));    // conj(w8)*O1
    float2 u2=make_float2(-O2.y, O2.x);                     // +i*O2
    float2 v3=make_float2(-c*(O3.x+O3.y), c*(O3.x-O3.y));   // conj(w8^3)*O3
    d[0] = f2add(E0,O0);
    d[1] = f2add(E1,t1);
    d[2] = f2add(E2,u2);
    d[3] = f2add(E3,v3);
    d[4] = f2sub(E0,O0);
    d[5] = f2sub(E1,t1);
    d[6] = f2sub(E2,u2);
    d[7] = f2sub(E3,v3);
}

// rounds B, C, D of forward FFT (round A done by caller in registers)
__device__ __forceinline__ void fft_fwd_rest(float2* s, const float4* __restrict__ tw12,
                                             const float2* __restrict__ tw3t, int tid){
    __syncthreads();
    {   // round B, stride 32
        int base = (tid>>5)*256 + (tid&31);
        float2 d[8];
#pragma unroll
        for (int q = 0; q < 8; ++q) d[q] = s[SW(base + 32*q)];
        r8f(d, tw12, tw3t, tid&31, 256);
#pragma unroll
        for (int q = 0; q < 8; ++q) s[SW(base + 32*q)] = d[q];
    }
    __syncthreads();
    {   // round C, stride 4
        int base = (tid>>2)*32 + (tid&3);
        float2 d[8];
#pragma unroll
        for (int q = 0; q < 8; ++q) d[q] = s[SW(base + 4*q)];
        r8f(d, tw12, tw3t, tid&3, 288);
#pragma unroll
        for (int q = 0; q < 8; ++q) s[SW(base + 4*q)] = d[q];
    }
    __syncthreads();
    {   // round D: radix-4 span-1, trivial twiddle, contiguous 8/thread
        int g8 = 8*tid;
#pragma unroll
        for (int h = 0; h < 2; ++h) {
            int b4 = g8 + 4*h;
            float2 x0=s[SW(b4)], x1=s[SW(b4+1)], x2=s[SW(b4+2)], x3=s[SW(b4+3)];
            float2 A0=f2add(x0,x2), A1=f2sub(x0,x2);
            float2 B0=f2add(x1,x3), B1=f2sub(x1,x3);
            s[SW(b4)]   = f2add(A0,B0);
            s[SW(b4+1)] = make_float2(A1.x + B1.y, A1.y - B1.x);  // A1 - i*B1
            s[SW(b4+2)] = f2sub(A0,B0);
            s[SW(b4+3)] = make_float2(A1.x - B1.y, A1.y + B1.x);  // A1 + i*B1
        }
    }
    __syncthreads();
}

// rounds D', C', B' of inverse FFT; caller does round A' in registers afterwards
__device__ __forceinline__ void fft_inv_rest(float2* s, const float4* __restrict__ tw12,
                                             const float2* __restrict__ tw3t, int tid){
    {   // radix-4 span-1 inverse
        int g8 = 8*tid;
#pragma unroll
        for (int h = 0; h < 2; ++h) {
            int b4 = g8 + 4*h;
            float2 z0=s[SW(b4)], z1=s[SW(b4+1)], z2=s[SW(b4+2)], z3=s[SW(b4+3)];
            float2 A0=f2add(z0,z2), A1=f2sub(z0,z2);
            float2 B0=f2add(z1,z3), B1=f2sub(z1,z3);
            s[SW(b4)]   = f2add(A0,B0);
            s[SW(b4+1)] = make_float2(A1.x - B1.y, A1.y + B1.x);  // A1 + i*B1
            s[SW(b4+2)] = f2sub(A0,B0);
            s[SW(b4+3)] = make_float2(A1.x + B1.y, A1.y - B1.x);  // A1 - i*B1
        }
    }
    __syncthreads();
    {   // C' stride 4
        int base = (tid>>2)*32 + (tid&3);
        float2 d[8];
#pragma unroll
        for (int q = 0; q < 8; ++q) d[q] = s[SW(base + 4*q)];
        r8i(d, tw12, tw3t, tid&3, 288);
#pragma unroll
        for (int q = 0; q < 8; ++q) s[SW(base + 4*q)] = d[q];
    }
    __syncthreads();
    {   // B' stride 32
        int base = (tid>>5)*256 + (tid&31);
        float2 d[8];
#pragma unroll
        for (int q = 0; q < 8; ++q) d[q] = s[SW(base + 32*q)];
        r8i(d, tw12, tw3t, tid&31, 256);
#pragma unroll
        for (int q = 0; q < 8; ++q) s[SW(base + 32*q)] = d[q];
    }
    __syncthreads();
}

// q = {th, ks, 1/kw, slope}; input is |X|^2
__device__ __forceinline__ float gr_of2(float a2, float4 q){
    float mag_db = 0.5f * DB_LOG2 * log2f(fmaxf(a2, 1e-16f));
    float over = mag_db - q.x;
    float hard = (mag_db < q.x) ? 0.0f : over*q.w;
    float kf = fminf(fmaxf((mag_db - q.y)*q.z, 0.0f), 1.0f);
    float kneeg = kf*kf*over*q.w;
    float ke = 2.0f*q.x - q.y;
    return (mag_db >= q.y && mag_db <= ke) ? kneeg : hard;
}

__device__ __forceinline__ float2 scale_bin(float2 X, float g){
    float a2 = X.x*X.x + X.y*X.y;
    if (a2 >= 1e-16f) return make_float2(g*X.x, g*X.y);
    if (a2 > 0.f)  { float sc = g*1e-8f*rsqrtf(a2); return make_float2(sc*X.x, sc*X.y); }
    return make_float2(g*1e-8f, 0.f);
}

// bin index for thread-order gain slot q (k_init only)
__device__ __forceinline__ int bin_of_q(int q){
    if (q >= 2048) return 1024;
    int jj = q >> 8, t = q & 255;
    int m = t + 256*(jj>>1);
    int k = revm(p_of_m(m));
    if (jj & 1) return (k == 0) ? 2048 : 2048 - k;
    return k;
}

// ---------------- init: twiddles + pair table {W, p, p2} + params + makeup ----------------
__global__ __launch_bounds__(NT) void k_init(
    const float* __restrict__ thr, const float* __restrict__ ratio,
    const float* __restrict__ knee, const float* __restrict__ makeup,
    float4* __restrict__ tw12, float2* __restrict__ tw3t,
    float4* __restrict__ wp, float4* __restrict__ pa, float4* __restrict__ pb,
    float* __restrict__ mkq)
{
    int i = blockIdx.x*NT + threadIdx.x;
    if (i < TWN) {
        int n, len;
        if (i < 256)      { n = i;       len = 2048; }
        else if (i < 288) { n = i - 256; len = 256;  }
        else              { n = i - 288; len = 32;   }
        double ang = -2.0*PI_D*(double)n/(double)len;
        tw12[i] = make_float4((float)cos(ang), (float)sin(ang),
                              (float)cos(2.0*ang), (float)sin(2.0*ang));
        tw3t[i] = make_float2((float)cos(3.0*ang), (float)sin(3.0*ang));
    } else if (i < TWN + 1024) {
        int m = i - TWN;
        int p  = p_of_m(m);
        int k  = revm(p);
        int k2 = (k == 0) ? 2048 : 2048 - k;
        int p2 = pmap((2048 - k) & 2047);
        double ang = -PI_D*(double)k/2048.0;   // E(k/4096)
        wp[m] = make_float4((float)cos(ang), (float)sin(ang),
                            __int_as_float(p), __int_as_float(p2));
        float th = thr[k], ra = ratio[k], kw = knee[k];
        pa[m] = make_float4(th, th - 0.5f*kw, 1.0f/kw, 1.0f - 1.0f/ra);
        th = thr[k2]; ra = ratio[k2]; kw = knee[k2];
        pb[m] = make_float4(th, th - 0.5f*kw, 1.0f/kw, 1.0f - 1.0f/ra);
    } else if (i < TWN + 1024 + NK) {
        int q = i - TWN - 1024;
        mkq[q] = exp2f(makeup[bin_of_q(q)] * DB2LIN_LOG2);   // 10^(mk/20)
    }
}

// ---------------- kernel 1: STFT (round A fused with load); spec pairs + gr ----------------
template<int STORESPEC>
__global__ __launch_bounds__(NT, 8) void k_fwd(
    const float* __restrict__ audio, const float* __restrict__ window,
    const float* __restrict__ thr, const float* __restrict__ ratio,
    const float* __restrict__ knee,
    const float4* __restrict__ tw12, const float2* __restrict__ tw3t,
    const float4* __restrict__ wp, const float4* __restrict__ pa,
    const float4* __restrict__ pb,
    float* __restrict__ gr, float4* __restrict__ spec)
{
    __shared__ float2 s[SWSZ];
    const int tid = threadIdx.x;
    const int blk = blockIdx.x;
    const int bc  = blk / NFRAMES;
    const int f   = blk - bc*NFRAMES;

    const float2* a2c = (const float2*)(audio + (size_t)bc*NSAMP + (size_t)f*NHOP);
    const float2* w2c = (const float2*)window;
    {   // fused load + round A (stride 256), registers only
        float2 d[8];
#pragma unroll
        for (int q = 0; q < 8; ++q) {
            int n = tid + 256*q;
            float2 u = a2c[n], w = w2c[n];
            d[q] = make_float2(u.x*w.x, u.y*w.y);     // z[n] = x[2n]w + i x[2n+1]w
        }
        r8f(d, tw12, tw3t, tid, 0);
#pragma unroll
        for (int q = 0; q < 8; ++q) s[SW(tid + 256*q)] = d[q];
    }
    fft_fwd_rest(s, tw12, tw3t, tid);

    const size_t row = ((size_t)bc*NFRAMES + f) * NK;
    float4* sp4 = spec + (size_t)(bc*NFRAMES + f) * CAST4;
#pragma unroll
    for (int j = 0; j < 4; ++j) {
        int m  = tid + NT*j;
        float4 wpv = wp[m];
        int p  = __float_as_int(wpv.z);
        int p2 = __float_as_int(wpv.w);
        float2 Zk  = s[SW(p)];
        float2 Zk2 = s[SW(p2)];
        float2 Ze = make_float2(0.5f*(Zk.x + Zk2.x), 0.5f*(Zk.y - Zk2.y));
        float2 Zo = make_float2(0.5f*(Zk.y + Zk2.y), -0.5f*(Zk.x - Zk2.x));
        float2 W  = make_float2(wpv.x, wpv.y);
        float2 V  = cmul(W, Zo);
        float2 Xk  = f2add(Ze, V);                              // X[k]
        float2 Xk2 = make_float2(Ze.x - V.x, V.y - Ze.y);       // X[2048-k]
        if (STORESPEC) sp4[m] = make_float4(Xk.x, Xk.y, Xk2.x, Xk2.y);
        gr[row + tid + NT*(2*j)]     = gr_of2(Xk.x*Xk.x + Xk.y*Xk.y,   pa[m]);
        gr[row + tid + NT*(2*j + 1)] = gr_of2(Xk2.x*Xk2.x + Xk2.y*Xk2.y, pb[m]);
    }
    if (tid == 0) {   // self-paired bin 1024 at slot pmap(1024)=2: X = conj(Z)
        float2 Z = s[SW(2)];
        if (STORESPEC) sp4[1024] = make_float4(Z.x, -Z.y, 0.f, 0.f);
        float th = thr[1024], ra = ratio[1024], kw = knee[1024];
        float4 q = make_float4(th, th - 0.5f*kw, 1.0f/kw, 1.0f - 1.0f/ra);
        gr[row + 2048] = gr_of2(Z.x*Z.x + Z.y*Z.y, q);
    }
}

// ---------------- kernel 2: attack/release scan; gr(dB) -> linear gain ----------------
__global__ __launch_bounds__(STH) void k_smooth(
    float* __restrict__ gr, const float* __restrict__ mkq)
{
    int gid = blockIdx.x*STH + threadIdx.x;
    if (gid >= NBC*NK) return;
    int bc = gid / NK;
    int q  = gid - bc*NK;
    float mkLin = mkq[q];
    float* p = gr + (size_t)bc*NFRAMES*NK + q;

    float env = 0.f;
    float cur[8], nxt[8];
#pragma unroll
    for (int d = 0; d < 8; ++d) cur[d] = p[(size_t)d*NK];
    for (int c = 0; c < NFRAMES; c += 8) {
#pragma unroll
        for (int d = 0; d < 8; ++d) {              // prefetch next batch early
            int fn = c + 8 + d;
            if (fn < NFRAMES) nxt[d] = p[(size_t)fn*NK];
        }
#pragma unroll
        for (int d = 0; d < 8; ++d)
            if (c + d < NFRAMES) cur[d] = exp2f(cur[d] * -DB2LIN_LOG2);  // tgt
#pragma unroll
        for (int d = 0; d < 8; ++d)
            if (c + d < NFRAMES) {
                float tgt = cur[d];
                float coeff = (tgt < env) ? A_COEFF : R_COEFF;
                env = fmaf(coeff, tgt - env, env);
                cur[d] = fmaxf(env, 1e-8f) * mkLin;   // linear gain (log/exp cancels)
            }
#pragma unroll
        for (int d = 0; d < 8; ++d)
            if (c + d < NFRAMES) p[(size_t)(c+d)*NK] = cur[d];
#pragma unroll
        for (int d = 0; d < 8; ++d) cur[d] = nxt[d];
    }
}

// repack scaled pair (XSk, XSk2) of bin k into packed-spectrum LDS slots (p, p2)
__device__ __forceinline__ void repack_pair(float2* s, float2 XSk, float2 XSk2,
                                            float2 W, int p, int p2){
    // Z'[k] = E + i*conj(W)*P ; Z'[k2] = conj(E) + i*W*conj(P)
    float2 E = make_float2(0.5f*(XSk.x + XSk2.x), 0.5f*(XSk.y - XSk2.y));
    float2 P = make_float2(0.5f*(XSk.x - XSk2.x), 0.5f*(XSk.y + XSk2.y));
    float2 Wc = make_float2(W.x, -W.y);
    float2 Q  = cmul(Wc, P);
    float2 Pc = make_float2(P.x, -P.y);
    float2 R  = cmul(W, Pc);
    s[SW(p)]  = make_float2(E.x - Q.y, E.y + Q.x);
    s[SW(p2)] = make_float2(E.x - R.y, R.x - E.y);
}

// MODE 0: read spec pairs, scale, repack, ifft; round A' ends in regs -> windowed ca write
// MODE 1: fallback — recompute fwd FFT from audio, unpack+scale+repack, ifft, RMW out
template<int MODE>
__global__ __launch_bounds__(NT, 8) void k_inv(
    const float* __restrict__ audio, const float* __restrict__ window,
    const float* __restrict__ gains,
    const float4* __restrict__ tw12, const float2* __restrict__ tw3t,
    const float4* __restrict__ wp,
    float4* __restrict__ spec, float* __restrict__ out, int pass, int nfp)
{
    __shared__ float2 s[SWSZ];
    const int tid = threadIdx.x;
    const int blk = blockIdx.x;
    int bc, f;
    if (MODE == 0) { bc = blk / NFRAMES; f = blk - bc*NFRAMES; }
    else           { bc = blk / nfp;     f = pass + 4*(blk - bc*nfp); }

    const float2* w2c = (const float2*)window;
    const float* g = gains + ((size_t)bc*NFRAMES + f) * NK;
    float4* sp4 = spec + (size_t)(bc*NFRAMES + f) * CAST4;

    if (MODE == 0) {
        // scale + repack directly from unpacked spec pairs (no FFT, no unpack)
#pragma unroll
        for (int j = 0; j < 4; ++j) {
            int m = tid + NT*j;
            float4 v = sp4[m];
            float4 wpv = wp[m];
            float2 XSk  = scale_bin(make_float2(v.x, v.y), g[tid + NT*(2*j)]);
            float2 XSk2 = scale_bin(make_float2(v.z, v.w), g[tid + NT*(2*j + 1)]);
            repack_pair(s, XSk, XSk2, make_float2(wpv.x, wpv.y),
                        __float_as_int(wpv.z), __float_as_int(wpv.w));
        }
        if (tid == 0) {
            float4 v = sp4[1024];
            float2 XS = scale_bin(make_float2(v.x, v.y), g[2048]);
            s[SW(2)] = make_float2(XS.x, -XS.y);     // Z' = conj(XS)
        }
        __syncthreads();
    } else {
        {   // fused load + forward round A
            const float2* a2c = (const float2*)(audio + (size_t)bc*NSAMP + (size_t)f*NHOP);
            float2 d[8];
#pragma unroll
            for (int q = 0; q < 8; ++q) {
                int n = tid + 256*q;
                float2 u = a2c[n], w = w2c[n];
                d[q] = make_float2(u.x*w.x, u.y*w.y);
            }
            r8f(d, tw12, tw3t, tid, 0);
#pragma unroll
            for (int q = 0; q < 8; ++q) s[SW(tid + 256*q)] = d[q];
        }
        fft_fwd_rest(s, tw12, tw3t, tid);
        // unpack + scale + repack in place
#pragma unroll
        for (int j = 0; j < 4; ++j) {
            int m = tid + NT*j;
            float4 wpv = wp[m];
            int p  = __float_as_int(wpv.z);
            int p2 = __float_as_int(wpv.w);
            float2 Zk  = s[SW(p)];
            float2 Zk2 = s[SW(p2)];
            float2 Ze = make_float2(0.5f*(Zk.x + Zk2.x), 0.5f*(Zk.y - Zk2.y));
            float2 Zo = make_float2(0.5f*(Zk.y + Zk2.y), -0.5f*(Zk.x - Zk2.x));
            float2 W  = make_float2(wpv.x, wpv.y);
            float2 V  = cmul(W, Zo);
            float2 Xk  = f2add(Ze, V);
            float2 Xk2 = make_float2(Ze.x - V.x, V.y - Ze.y);
            float2 XSk  = scale_bin(Xk,  g[tid + NT*(2*j)]);
            float2 XSk2 = scale_bin(Xk2, g[tid + NT*(2*j + 1)]);
            repack_pair(s, XSk, XSk2, W, p, p2);
        }
        if (tid == 0) {
            float2 Z  = s[SW(2)];
            float2 XS = scale_bin(make_float2(Z.x, -Z.y), g[2048]);
            s[SW(2)] = make_float2(XS.x, -XS.y);
        }
        __syncthreads();
    }

    fft_inv_rest(s, tw12, tw3t, tid);

    const float invn = 1.0f/2048.0f;
    {   // round A' (stride 256) in registers -> global write
        float2 d[8];
#pragma unroll
        for (int q = 0; q < 8; ++q) d[q] = s[SW(tid + 256*q)];
        r8i(d, tw12, tw3t, tid, 0);
        if (MODE == 0) {
            float2* ca2 = (float2*)sp4;          // overwrite spec row with windowed ca
#pragma unroll
            for (int q = 0; q < 8; ++q) {
                int n = tid + 256*q;
                float2 w = w2c[n];
                ca2[n] = make_float2(d[q].x*w.x*invn, d[q].y*w.y*invn);
            }
        } else {
            float2* dst2 = (float2*)(out + (size_t)bc*NSAMP + (size_t)f*NHOP);
#pragma unroll
            for (int q = 0; q < 8; ++q) {
                int n = tid + 256*q;
                float2 w = w2c[n];
                float2 o = dst2[n];
                o.x += d[q].x * w.x * invn;
                o.y += d[q].y * w.y * invn;
                dst2[n] = o;
            }
        }
    }
}

// ---------------- kernel 4: overlap-add gather (each ca byte read exactly once) ----------------
__global__ __launch_bounds__(NT) void k_ola(
    const float* __restrict__ ca, float* __restrict__ out)
{
    const int blk = blockIdx.x;
    const int bc = blk >> 9;          // 512 tiles of 1024 samples
    const int ti = blk & 511;
    const int tid = threadIdx.x;
    float4 acc = make_float4(0.f, 0.f, 0.f, 0.f);
    int flo = ti - 3; if (flo < 0) flo = 0;
    int fhi = ti; if (fhi > NFRAMES - 1) fhi = NFRAMES - 1;
    for (int f = flo; f <= fhi; ++f) {
        const float4* row = (const float4*)(ca + ((size_t)bc*NFRAMES + f) * (4*CAST4));
        float4 v = row[(ti - f)*256 + tid];
        acc.x += v.x; acc.y += v.y; acc.z += v.z; acc.w += v.w;
    }
    ((float4*)(out + (size_t)bc*NSAMP))[ti*256 + tid] = acc;
}

extern "C" void kernel_launch(void* const* d_in, const int* in_sizes, int n_in,
                              void* d_out, int out_size, void* d_ws, size_t ws_size,
                              hipStream_t stream)
{
    const float* audio  = (const float*)d_in[0];
    const float* window = (const float*)d_in[1];
    const float* thr    = (const float*)d_in[2];
    const float* ratio  = (const float*)d_in[3];
    const float* makeup = (const float*)d_in[4];
    const float* knee   = (const float*)d_in[5];
    float* out = (float*)d_out;

    float4* tw12 = (float4*)d_ws;
    float2* tw3t = (float2*)((char*)d_ws + 8192);
    float4* wp   = (float4*)((char*)d_ws + 16384);
    float4* pa   = (float4*)((char*)d_ws + 32768);
    float4* pb   = (float4*)((char*)d_ws + 49152);
    float*  mkq  = (float*)((char*)d_ws + 65536);
    float*  gr   = (float*)((char*)d_ws + WSHDR);
    size_t grBytes = (size_t)NBC*NFRAMES*NK*sizeof(float);
    float4* spec = (float4*)((char*)d_ws + WSHDR + grBytes);
    size_t need = WSHDR + grBytes + (size_t)NBC*NFRAMES*CAST4*sizeof(float4);
    int hasSpec = (ws_size >= need) ? 1 : 0;

    dim3 blkd(NT);
    k_init<<<dim3((TWN + 1024 + NK + NT - 1)/NT), blkd, 0, stream>>>(
        thr, ratio, knee, makeup, tw12, tw3t, wp, pa, pb, mkq);

    if (hasSpec) {
        k_fwd<1><<<dim3(NBC*NFRAMES), blkd, 0, stream>>>(
            audio, window, thr, ratio, knee, tw12, tw3t, wp, pa, pb, gr, spec);
        k_smooth<<<dim3((NBC*NK + STH - 1)/STH), dim3(STH), 0, stream>>>(gr, mkq);
        k_inv<0><<<dim3(NBC*NFRAMES), blkd, 0, stream>>>(
            audio, window, gr, tw12, tw3t, wp, spec, out, 0, 0);
        k_ola<<<dim3(NBC*512), blkd, 0, stream>>>((const float*)spec, out);
    } else {
        hipMemsetAsync(d_out, 0, (size_t)out_size*sizeof(float), stream);
        k_fwd<0><<<dim3(NBC*NFRAMES), blkd, 0, stream>>>(
            audio, window, thr, ratio, knee, tw12, tw3t, wp, pa, pb, gr, spec);
        k_smooth<<<dim3((NBC*NK + STH - 1)/STH), dim3(STH), 0, stream>>>(gr, mkq);
        for (int pass = 0; pass < 4; ++pass) {
            int nfp = (NFRAMES - pass + 3) / 4;
            k_inv<1><<<dim3(NBC*nfp), blkd, 0, stream>>>(
                audio, window, gr, tw12, tw3t, wp, spec, out, pass, nfp);
        }
    }
}